// Round 6
// baseline (1045.720 us; speedup 1.0000x reference)
//
#include <hip/hip_runtime.h>

typedef unsigned short u16;
typedef unsigned int u32;
typedef short bf16x8 __attribute__((ext_vector_type(8)));
typedef float f32x4 __attribute__((ext_vector_type(4)));

__device__ __forceinline__ float bf2f(u16 h) {
    union { u32 i; float f; } v; v.i = ((u32)h) << 16; return v.f;
}
__device__ __forceinline__ u16 f2bf(float f) {
    union { float f; u32 i; } v; v.f = f;
    u32 i = v.i;
    return (u16)((i + 0x7fffu + ((i >> 16) & 1u)) >> 16);
}

// Async global->LDS 16B per lane. LDS dest = wave-uniform base + lane*16.
typedef __attribute__((address_space(1))) const unsigned int ga_u32;
typedef __attribute__((address_space(3))) unsigned int ls_u32;
__device__ __forceinline__ void async16(const void* g, void* l) {
    __builtin_amdgcn_global_load_lds((ga_u32*)g, (ls_u32*)l, 16, 0, 0);
}

struct InPtrs { const void* p[22]; int n[22]; };

// ---------------------------------------------------------------------------
// Dtype sniffer (one block per tensor): flags[t]=1 if tensor t looks like
// packed f32, 0 if bf16. flags[22] = output dtype := flags[0].
// ---------------------------------------------------------------------------
__global__ void sniff_k(InPtrs ip, u32* flags) {
    int t = blockIdx.x;
    __shared__ int s_susp, s_zero;
    if (threadIdx.x == 0) { s_susp = 0; s_zero = 0; }
    __syncthreads();
    int n = ip.n[t];
    int S = n < 4096 ? n : 4096;
    const u16* p = (const u16*)ip.p[t];
    int susp = 0, zero = 0;
    for (int i = threadIdx.x; i < S; i += 256) {
        u16 w = p[i];
        if (w == 0) zero++;
        else { int e = (w >> 7) & 0xFF; if (e < 90 || e > 150) susp++; }
    }
    atomicAdd(&s_susp, susp);
    atomicAdd(&s_zero, zero);
    __syncthreads();
    if (threadIdx.x == 0) {
        float fs = (float)s_susp / (float)S;
        float fz = (float)s_zero / (float)S;
        u32 f = (fs > 0.10f || (fz > 0.30f && fz < 0.70f)) ? 1u : 0u;
        flags[t] = f;
        if (t == 0) flags[22] = f;
    }
}

// ---------------------------------------------------------------------------
// Fused small-tensor convert: 10 contiguous segments -> SM (bf16)
// ---------------------------------------------------------------------------
struct ConvDesc { const void* src[10]; int fidx[10]; int n[10]; };

__global__ void convall_k(ConvDesc cd, const u32* __restrict__ flags,
                          u16* __restrict__ dst, int total) {
    int i = blockIdx.x * 256 + threadIdx.x;
    if (i >= total) return;
    int s = 0, start = 0;
    while (i >= start + cd.n[s]) { start += cd.n[s]; s++; }
    int off = i - start;
    const void* sp = cd.src[s];
    dst[i] = flags[cd.fidx[s]] ? f2bf(((const float*)sp)[off]) : ((const u16*)sp)[off];
}

// ---------------------------------------------------------------------------
// Context copy into zero-padded [4][128][768] bf16 buffer
// ---------------------------------------------------------------------------
__global__ void ctxcopy_k(const void* ctx, const u32* __restrict__ flags,
                          u16* __restrict__ ctxp) {
    int idx = blockIdx.x * 256 + threadIdx.x;
    if (idx < 4 * 77 * 768) {
        int c = idx % 768;
        int t = (idx / 768) % 77;
        int b = idx / (768 * 77);
        u16 v = flags[1] ? f2bf(((const float*)ctx)[idx]) : ((const u16*)ctx)[idx];
        ctxp[((size_t)b * 128 + t) * 768 + c] = v;
    }
}

// ---------------------------------------------------------------------------
// Weight transpose+convert: src [R][ld] (flagged dtype) -> dst [C][R] bf16
// ---------------------------------------------------------------------------
__global__ void transpose_k(const void* src, const u32* __restrict__ flags, int fidx,
                            int R, int C, int ld, u16* __restrict__ dst) {
    __shared__ u16 tile[32][33];
    int c0 = blockIdx.x * 32, r0 = blockIdx.y * 32;
    int tx = threadIdx.x, ty = threadIdx.y;
    bool f = flags[fidx] != 0;
#pragma unroll
    for (int i = 0; i < 4; i++) {
        size_t idx = (size_t)(r0 + ty + i * 8) * ld + c0 + tx;
        tile[ty + i * 8][tx] = f ? f2bf(((const float*)src)[idx]) : ((const u16*)src)[idx];
    }
    __syncthreads();
#pragma unroll
    for (int i = 0; i < 4; i++)
        dst[(size_t)(c0 + ty + i * 8) * R + r0 + tx] = tile[tx][ty + i * 8];
}

// ---------------------------------------------------------------------------
// Per-head V transpose: V[(b*rpb + j)*1024 + h*64 + d] -> VT[(bh*64+d)*rpb + j]
// ---------------------------------------------------------------------------
__global__ void vtrans_k(const u16* __restrict__ V, u16* __restrict__ VT, int rpb) {
    __shared__ u16 tile[32][33];
    int bh = blockIdx.z; int b = bh >> 4, h = bh & 15;
    int j0 = blockIdx.x * 32, d0 = blockIdx.y * 32;
    int tx = threadIdx.x, ty = threadIdx.y;
#pragma unroll
    for (int i = 0; i < 4; i++)
        tile[ty + i * 8][tx] = V[(size_t)(b * rpb + j0 + ty + i * 8) * 1024 + h * 64 + d0 + tx];
    __syncthreads();
#pragma unroll
    for (int i = 0; i < 4; i++)
        VT[((size_t)bh * 64 + d0 + ty + i * 8) * rpb + j0 + tx] = tile[tx][ty + i * 8];
}

// ---------------------------------------------------------------------------
// LayerNorm over rows of 1024.
// ---------------------------------------------------------------------------
__global__ void __launch_bounds__(256) ln_kernel(
    const void* src, int sfidx, void* res_out, u16* __restrict__ xn_out,
    const u16* __restrict__ gw, const u16* __restrict__ bw,
    const u32* __restrict__ flags) {
    int row = blockIdx.x, tid = threadIdx.x;
    size_t base = (size_t)row * 1024;
    bool sf = flags[sfidx] != 0;
    bool of = flags[22] != 0;
    float v[4];
#pragma unroll
    for (int k = 0; k < 4; k++) {
        size_t idx = base + tid + k * 256;
        v[k] = sf ? ((const float*)src)[idx] : bf2f(((const u16*)src)[idx]);
    }
    if (res_out) {
#pragma unroll
        for (int k = 0; k < 4; k++) {
            size_t idx = base + tid + k * 256;
            if (of) ((float*)res_out)[idx] = v[k];
            else ((u16*)res_out)[idx] = f2bf(v[k]);
        }
    }
    float s = 0.f, ss = 0.f;
#pragma unroll
    for (int k = 0; k < 4; k++) { s += v[k]; ss += v[k] * v[k]; }
    for (int off = 32; off; off >>= 1) {
        s += __shfl_down(s, off);
        ss += __shfl_down(ss, off);
    }
    __shared__ float rs[4], rss[4];
    int wave = tid >> 6, lane = tid & 63;
    if (lane == 0) { rs[wave] = s; rss[wave] = ss; }
    __syncthreads();
    s = rs[0] + rs[1] + rs[2] + rs[3];
    ss = rss[0] + rss[1] + rss[2] + rss[3];
    float mean = s * (1.f / 1024.f);
    float var = ss * (1.f / 1024.f) - mean * mean;
    float rstd = rsqrtf(var + 1e-5f);
#pragma unroll
    for (int k = 0; k < 4; k++) {
        int c = tid + k * 256;
        xn_out[base + c] = f2bf((v[k] - mean) * rstd * bf2f(gw[c]) + bf2f(bw[c]));
    }
}

// ---------------------------------------------------------------------------
// 128x128-tile bf16 MFMA GEMM, BK=32 (m97-canonical), async global_load_lds
// width-16 staging, 16 KB LDS/block for high occupancy (~5 blocks/CU).
// Staging pointers hoisted and incremented (+32/iter) to minimize VALU.
// BT = B^T stored [N][K].
// MODE 0: Cout(bf16) = acc + bias?
// MODE 1: Res(dtype flags[22]) = acc + bias + Res  (in-place residual)
// MODE 3: Cout(bf16) = (acc + bias) * gelu(Gbuf)
// M%128==0, N%128==0, K%32==0.
// ---------------------------------------------------------------------------
template <int MODE>
__global__ void __launch_bounds__(256) gemm128(
    const u16* __restrict__ A, const u16* __restrict__ BT,
    u16* Cout, void* Res, const u16* __restrict__ bias, const u16* Gbuf,
    const u32* __restrict__ flags, int M, int N, int K) {
    __shared__ alignas(16) u16 As[128 * 32];
    __shared__ alignas(16) u16 Bs[128 * 32];
    int tid = threadIdx.x;
    int row0 = blockIdx.y * 128, col0 = blockIdx.x * 128;
    int wave = tid >> 6, lane = tid & 63, q = lane >> 4, ln = lane & 15;
    int wr = (wave >> 1) * 64, wc = (wave & 1) * 64;
    int l4r = lane >> 2, l4c = (lane & 3) * 8;   // staging: 4 lanes/row
    bool of = (MODE == 1) ? (flags[22] != 0) : false;

    // hoisted staging pointers (advance by 32 each K-iter)
    const u16* pA = A + (size_t)(row0 + wave * 32 + l4r) * K + l4c;
    const u16* pB = BT + (size_t)(col0 + wave * 32 + l4r) * K + l4c;
    u16* lA0 = &As[(wave * 32) * 32];
    u16* lA1 = &As[(wave * 32 + 16) * 32];
    u16* lB0 = &Bs[(wave * 32) * 32];
    u16* lB1 = &Bs[(wave * 32 + 16) * 32];
    const size_t rowStep = (size_t)16 * K;

    f32x4 acc[4][4] = {};

    for (int k0 = 0; k0 < K; k0 += 32) {
        async16(pA, lA0);
        async16(pA + rowStep, lA1);
        async16(pB, lB0);
        async16(pB + rowStep, lB1);
        pA += 32; pB += 32;
        __syncthreads();
        bf16x8 af[4], bfr[4];
#pragma unroll
        for (int mi = 0; mi < 4; mi++)
            af[mi] = *(const bf16x8*)(&As[(wr + mi * 16 + ln) * 32 + q * 8]);
#pragma unroll
        for (int ni = 0; ni < 4; ni++)
            bfr[ni] = *(const bf16x8*)(&Bs[(wc + ni * 16 + ln) * 32 + q * 8]);
#pragma unroll
        for (int mi = 0; mi < 4; mi++)
#pragma unroll
            for (int ni = 0; ni < 4; ni++)
                acc[mi][ni] = __builtin_amdgcn_mfma_f32_16x16x32_bf16(
                    af[mi], bfr[ni], acc[mi][ni], 0, 0, 0);
        __syncthreads();
    }

#pragma unroll
    for (int mi = 0; mi < 4; mi++) {
#pragma unroll
        for (int ni = 0; ni < 4; ni++) {
            int col = col0 + wc + ni * 16 + ln;
            float bv = bias ? bf2f(bias[col]) : 0.f;
#pragma unroll
            for (int r = 0; r < 4; r++) {
                int row = row0 + wr + mi * 16 + q * 4 + r;
                size_t idx = (size_t)row * N + col;
                float v = acc[mi][ni][r] + bv;
                if (MODE == 0) {
                    Cout[idx] = f2bf(v);
                } else if (MODE == 1) {
                    if (of) {
                        float* R = (float*)Res;
                        R[idx] = v + R[idx];
                    } else {
                        u16* R = (u16*)Res;
                        R[idx] = f2bf(v + bf2f(R[idx]));
                    }
                } else {  // MODE 3
                    float g = bf2f(Gbuf[idx]);
                    float ge = 0.5f * g * (1.f + erff(g * 0.70710678118f));
                    Cout[idx] = f2bf(v * ge);
                }
            }
        }
    }
}

// ---------------------------------------------------------------------------
// Flash attention: O in place over Q. K [rows][1024]; VT per-head [64][vt_ld].
// Async width-16 staging into two-plane LDS tiles [2][64][32].
// No-running-max softmax (scores bounded for this problem), deferred row-sum.
// grid (32 q-tiles, 64 batch*head), block 256.
// ---------------------------------------------------------------------------
__global__ void __launch_bounds__(256) attn_kernel(
    u16* Q, const u16* __restrict__ K, const u16* __restrict__ VT,
    int nkv, int kv_rpb, int vt_ld, float scale) {
    __shared__ alignas(16) u16 ktile[2][64 * 32];   // plane d-half: [key j][d%32]
    __shared__ alignas(16) u16 vtile[2][64 * 32];   // plane j-half: [d][j%32]
    __shared__ alignas(16) u16 pbuf[4][16 * 72];

    int tid = threadIdx.x, wave = tid >> 6, lane = tid & 63;
    int q = lane >> 4, ln = lane & 15;
    int l4r = lane >> 2, l4c = (lane & 3) * 8;
    int bh = blockIdx.y; int b = bh >> 4, h = bh & 15;
    int qt = blockIdx.x;
    int qrow0 = b * 2048 + qt * 64 + wave * 16;

    u16* Qbase = Q + (size_t)(qrow0 + ln) * 1024 + h * 64;
    bf16x8 qf0 = *(const bf16x8*)(Qbase + q * 8);
    bf16x8 qf1 = *(const bf16x8*)(Qbase + 32 + q * 8);

    f32x4 oacc[4] = {};
    float lsum[4] = {0.f, 0.f, 0.f, 0.f};

    const u16* Kb = K + (size_t)b * kv_rpb * 1024 + h * 64;
    const u16* VTb = VT + (size_t)bh * 64 * vt_ld;
    int nkt = (nkv + 63) >> 6;

    for (int t = 0; t < nkt; ++t) {
        int j0 = t * 64;
        int rbase = wave * 16;
#pragma unroll
        for (int half = 0; half < 2; half++) {
            async16(Kb + (size_t)(j0 + rbase + l4r) * 1024 + half * 32 + l4c,
                    &ktile[half][rbase * 32]);
            async16(VTb + (size_t)(rbase + l4r) * vt_ld + j0 + half * 32 + l4c,
                    &vtile[half][rbase * 32]);
        }
        __syncthreads();

        f32x4 s[4] = {};
#pragma unroll
        for (int ni = 0; ni < 4; ni++) {
            bf16x8 k0f = *(const bf16x8*)(&ktile[0][(ni * 16 + ln) * 32 + q * 8]);
            bf16x8 k1f = *(const bf16x8*)(&ktile[1][(ni * 16 + ln) * 32 + q * 8]);
            s[ni] = __builtin_amdgcn_mfma_f32_16x16x32_bf16(qf0, k0f, s[ni], 0, 0, 0);
            s[ni] = __builtin_amdgcn_mfma_f32_16x16x32_bf16(qf1, k1f, s[ni], 0, 0, 0);
        }

        u16* pb = pbuf[wave];
#pragma unroll
        for (int ni = 0; ni < 4; ni++) {
            bool valid = (j0 + ni * 16 + ln) < nkv;
#pragma unroll
            for (int r = 0; r < 4; r++) {
                float e = valid ? __expf(s[ni][r] * scale) : 0.f;
                lsum[r] += e;
                union { float f; u32 i; } u; u.f = e;
                pb[(q * 4 + r) * 72 + ni * 16 + ln] = (u16)(u.i >> 16);
            }
        }
        __syncthreads();

        bf16x8 pf0 = *(const bf16x8*)(pb + ln * 72 + q * 8);
        bf16x8 pf1 = *(const bf16x8*)(pb + ln * 72 + 32 + q * 8);
#pragma unroll
        for (int nd = 0; nd < 4; nd++) {
            bf16x8 v0 = *(const bf16x8*)(&vtile[0][(nd * 16 + ln) * 32 + q * 8]);
            bf16x8 v1 = *(const bf16x8*)(&vtile[1][(nd * 16 + ln) * 32 + q * 8]);
            oacc[nd] = __builtin_amdgcn_mfma_f32_16x16x32_bf16(pf0, v0, oacc[nd], 0, 0, 0);
            oacc[nd] = __builtin_amdgcn_mfma_f32_16x16x32_bf16(pf1, v1, oacc[nd], 0, 0, 0);
        }
        __syncthreads();
    }

#pragma unroll
    for (int r = 0; r < 4; r++) {
        float l = lsum[r];
        l += __shfl_xor(l, 1);
        l += __shfl_xor(l, 2);
        l += __shfl_xor(l, 4);
        l += __shfl_xor(l, 8);
        float inv = 1.f / l;
#pragma unroll
        for (int nd = 0; nd < 4; nd++)
            Q[(size_t)(qrow0 + q * 4 + r) * 1024 + h * 64 + nd * 16 + ln] =
                f2bf(oacc[nd][r] * inv);
    }
}

// ---------------------------------------------------------------------------
// Workspace layout (byte offsets).  Total 97 MiB.
// ---------------------------------------------------------------------------
static constexpr size_t MB = 1048576;
static constexpr size_t OFF_FLAGS = 0;
static constexpr size_t OFF_SMALL = 4096;
static constexpr size_t OFF_CTXP = 65536;
static constexpr size_t OFF_WT = 1 * MB;
static constexpr size_t OFF_XN = 17 * MB;
static constexpr size_t OFF_Q = 33 * MB;
static constexpr size_t OFF_K = 49 * MB;
static constexpr size_t OFF_V = 65 * MB;
static constexpr size_t OFF_VT = 81 * MB;

static constexpr int SM_BO1 = 0, SM_BO2 = 1024, SM_BFF1 = 2048, SM_BFF2 = 10240;
static constexpr int SM_G1 = 11264, SM_BE1 = 12288, SM_G2 = 13312, SM_BE2 = 14336;
static constexpr int SM_G3 = 15360, SM_BE3 = 16384;
static constexpr int SM_TOTAL = 17408;

extern "C" void kernel_launch(void* const* d_in, const int* in_sizes, int n_in,
                              void* d_out, int out_size, void* d_ws, size_t ws_size,
                              hipStream_t stream) {
    (void)out_size; (void)ws_size; (void)n_in;
    char* w = (char*)d_ws;
    u32* flags = (u32*)(w + OFF_FLAGS);
    u16* SM = (u16*)(w + OFF_SMALL);
    u16* ctxp = (u16*)(w + OFF_CTXP);
    u16* WT = (u16*)(w + OFF_WT);
    u16* xn = (u16*)(w + OFF_XN);
    u16* Qb = (u16*)(w + OFF_Q);
    u16* Kb = (u16*)(w + OFF_K);
    u16* Vb = (u16*)(w + OFF_V);
    u16* VTb = (u16*)(w + OFF_VT);
    u16* hb = Qb;  // [8192][4096] spans Q..97MB (stage 3)

    InPtrs ip;
    for (int i = 0; i < 22; i++) { ip.p[i] = d_in[i]; ip.n[i] = in_sizes[i]; }
    sniff_k<<<22, 256, 0, stream>>>(ip, flags);

    ConvDesc cd;
    const int srcs[10] = {6, 11, 13, 15, 16, 17, 18, 19, 20, 21};
    const int lens[10] = {1024, 1024, 8192, 1024, 1024, 1024, 1024, 1024, 1024, 1024};
    for (int i = 0; i < 10; i++) { cd.src[i] = d_in[srcs[i]]; cd.fidx[i] = srcs[i]; cd.n[i] = lens[i]; }
    convall_k<<<(SM_TOTAL + 255) / 256, 256, 0, stream>>>(cd, flags, SM, SM_TOTAL);

    hipMemsetAsync(ctxp, 0, 512ull * 768 * 2, stream);
    ctxcopy_k<<<(4 * 77 * 768 + 255) / 256, 256, 0, stream>>>(d_in[1], flags, ctxp);

    dim3 b32(32, 8);
    const size_t M1 = 1048576;

    // ---------------- stage 1: self attention ----------------
    transpose_k<<<dim3(32, 32), b32, 0, stream>>>(d_in[2], flags, 2, 1024, 1024, 1024, WT + 0 * M1);
    transpose_k<<<dim3(32, 32), b32, 0, stream>>>(d_in[3], flags, 3, 1024, 1024, 1024, WT + 1 * M1);
    transpose_k<<<dim3(32, 32), b32, 0, stream>>>(d_in[4], flags, 4, 1024, 1024, 1024, WT + 2 * M1);
    transpose_k<<<dim3(32, 32), b32, 0, stream>>>(d_in[5], flags, 5, 1024, 1024, 1024, WT + 3 * M1);

    ln_kernel<<<8192, 256, 0, stream>>>(d_in[0], 0, d_out, xn, SM + SM_G1, SM + SM_BE1, flags);
    gemm128<0><<<dim3(8, 64), 256, 0, stream>>>(xn, WT + 0 * M1, Qb, nullptr, nullptr, nullptr, flags, 8192, 1024, 1024);
    gemm128<0><<<dim3(8, 64), 256, 0, stream>>>(xn, WT + 1 * M1, Kb, nullptr, nullptr, nullptr, flags, 8192, 1024, 1024);
    gemm128<0><<<dim3(8, 64), 256, 0, stream>>>(xn, WT + 2 * M1, Vb, nullptr, nullptr, nullptr, flags, 8192, 1024, 1024);
    vtrans_k<<<dim3(64, 2, 64), b32, 0, stream>>>(Vb, VTb, 2048);
    attn_kernel<<<dim3(32, 64), 256, 0, stream>>>(Qb, Kb, VTb, 2048, 2048, 2048, 0.125f);
    gemm128<1><<<dim3(8, 64), 256, 0, stream>>>(Qb, WT + 3 * M1, nullptr, d_out, SM + SM_BO1, nullptr, flags, 8192, 1024, 1024);

    // ---------------- stage 2: cross attention ----------------
    transpose_k<<<dim3(32, 32), b32, 0, stream>>>(d_in[7], flags, 7, 1024, 1024, 1024, WT + 0 * M1);
    transpose_k<<<dim3(32, 24), b32, 0, stream>>>(d_in[8], flags, 8, 768, 1024, 1024, WT + 1 * M1);
    transpose_k<<<dim3(32, 24), b32, 0, stream>>>(d_in[9], flags, 9, 768, 1024, 1024, WT + 2 * M1);
    transpose_k<<<dim3(32, 32), b32, 0, stream>>>(d_in[10], flags, 10, 1024, 1024, 1024, WT + 3 * M1);

    ln_kernel<<<8192, 256, 0, stream>>>(d_out, 22, nullptr, xn, SM + SM_G2, SM + SM_BE2, flags);
    gemm128<0><<<dim3(8, 64), 256, 0, stream>>>(xn, WT + 0 * M1, Qb, nullptr, nullptr, nullptr, flags, 8192, 1024, 1024);
    gemm128<0><<<dim3(8, 4), 256, 0, stream>>>(ctxp, WT + 1 * M1, Kb, nullptr, nullptr, nullptr, flags, 512, 1024, 768);
    gemm128<0><<<dim3(8, 4), 256, 0, stream>>>(ctxp, WT + 2 * M1, Vb, nullptr, nullptr, nullptr, flags, 512, 1024, 768);
    vtrans_k<<<dim3(4, 2, 64), b32, 0, stream>>>(Vb, VTb, 128);
    attn_kernel<<<dim3(32, 64), 256, 0, stream>>>(Qb, Kb, VTb, 77, 128, 128, 0.125f);
    gemm128<1><<<dim3(8, 64), 256, 0, stream>>>(Qb, WT + 3 * M1, nullptr, d_out, SM + SM_BO2, nullptr, flags, 8192, 1024, 1024);

    // ---------------- stage 3: GEGLU FF ----------------
    ln_kernel<<<8192, 256, 0, stream>>>(d_out, 22, nullptr, xn, SM + SM_G3, SM + SM_BE3, flags);
    transpose_k<<<dim3(256, 32), b32, 0, stream>>>(d_in[12], flags, 12, 1024, 8192, 8192, WT);
    gemm128<0><<<dim3(32, 64), 256, 0, stream>>>(xn, WT + 4096ull * 1024, hb, nullptr, SM + SM_BFF1 + 4096, nullptr, flags, 8192, 4096, 1024);
    gemm128<3><<<dim3(32, 64), 256, 0, stream>>>(xn, WT, hb, nullptr, SM + SM_BFF1, hb, flags, 8192, 4096, 1024);
    transpose_k<<<dim3(32, 128), b32, 0, stream>>>(d_in[14], flags, 14, 4096, 1024, 1024, WT);
    gemm128<1><<<dim3(8, 64), 256, 0, stream>>>(hb, WT, nullptr, d_out, SM + SM_BFF2, nullptr, flags, 8192, 1024, 4096);
}

// Round 7
// 1014.748 us; speedup vs baseline: 1.0305x; 1.0305x over previous
//
#include <hip/hip_runtime.h>

typedef unsigned short u16;
typedef unsigned int u32;
typedef short bf16x8 __attribute__((ext_vector_type(8)));
typedef float f32x4 __attribute__((ext_vector_type(4)));

__device__ __forceinline__ float bf2f(u16 h) {
    union { u32 i; float f; } v; v.i = ((u32)h) << 16; return v.f;
}
__device__ __forceinline__ u16 f2bf(float f) {
    union { float f; u32 i; } v; v.f = f;
    u32 i = v.i;
    return (u16)((i + 0x7fffu + ((i >> 16) & 1u)) >> 16);
}

// Async global->LDS 16B per lane. LDS dest = wave-uniform base + lane*16.
typedef __attribute__((address_space(1))) const unsigned int ga_u32;
typedef __attribute__((address_space(3))) unsigned int ls_u32;
__device__ __forceinline__ void async16(const void* g, void* l) {
    __builtin_amdgcn_global_load_lds((ga_u32*)g, (ls_u32*)l, 16, 0, 0);
}

struct InPtrs { const void* p[22]; int n[22]; };

// ---------------------------------------------------------------------------
// Dtype sniffer (one block per tensor): flags[t]=1 if tensor t looks like
// packed f32, 0 if bf16. flags[22] = output dtype := flags[0].
// ---------------------------------------------------------------------------
__global__ void sniff_k(InPtrs ip, u32* flags) {
    int t = blockIdx.x;
    __shared__ int s_susp, s_zero;
    if (threadIdx.x == 0) { s_susp = 0; s_zero = 0; }
    __syncthreads();
    int n = ip.n[t];
    int S = n < 4096 ? n : 4096;
    const u16* p = (const u16*)ip.p[t];
    int susp = 0, zero = 0;
    for (int i = threadIdx.x; i < S; i += 256) {
        u16 w = p[i];
        if (w == 0) zero++;
        else { int e = (w >> 7) & 0xFF; if (e < 90 || e > 150) susp++; }
    }
    atomicAdd(&s_susp, susp);
    atomicAdd(&s_zero, zero);
    __syncthreads();
    if (threadIdx.x == 0) {
        float fs = (float)s_susp / (float)S;
        float fz = (float)s_zero / (float)S;
        u32 f = (fs > 0.10f || (fz > 0.30f && fz < 0.70f)) ? 1u : 0u;
        flags[t] = f;
        if (t == 0) flags[22] = f;
    }
}

// ---------------------------------------------------------------------------
// Fused small-tensor convert: 10 contiguous segments -> SM (bf16)
// ---------------------------------------------------------------------------
struct ConvDesc { const void* src[10]; int fidx[10]; int n[10]; };

__global__ void convall_k(ConvDesc cd, const u32* __restrict__ flags,
                          u16* __restrict__ dst, int total) {
    int i = blockIdx.x * 256 + threadIdx.x;
    if (i >= total) return;
    int s = 0, start = 0;
    while (i >= start + cd.n[s]) { start += cd.n[s]; s++; }
    int off = i - start;
    const void* sp = cd.src[s];
    dst[i] = flags[cd.fidx[s]] ? f2bf(((const float*)sp)[off]) : ((const u16*)sp)[off];
}

// ---------------------------------------------------------------------------
// Context copy into zero-padded [4][128][768] bf16 buffer
// ---------------------------------------------------------------------------
__global__ void ctxcopy_k(const void* ctx, const u32* __restrict__ flags,
                          u16* __restrict__ ctxp) {
    int idx = blockIdx.x * 256 + threadIdx.x;
    if (idx < 4 * 77 * 768) {
        int c = idx % 768;
        int t = (idx / 768) % 77;
        int b = idx / (768 * 77);
        u16 v = flags[1] ? f2bf(((const float*)ctx)[idx]) : ((const u16*)ctx)[idx];
        ctxp[((size_t)b * 128 + t) * 768 + c] = v;
    }
}

// ---------------------------------------------------------------------------
// Weight transpose+convert: src [R][ld] (flagged dtype) -> dst [C][R] bf16
// ---------------------------------------------------------------------------
__global__ void transpose_k(const void* src, const u32* __restrict__ flags, int fidx,
                            int R, int C, int ld, u16* __restrict__ dst) {
    __shared__ u16 tile[32][33];
    int c0 = blockIdx.x * 32, r0 = blockIdx.y * 32;
    int tx = threadIdx.x, ty = threadIdx.y;
    bool f = flags[fidx] != 0;
#pragma unroll
    for (int i = 0; i < 4; i++) {
        size_t idx = (size_t)(r0 + ty + i * 8) * ld + c0 + tx;
        tile[ty + i * 8][tx] = f ? f2bf(((const float*)src)[idx]) : ((const u16*)src)[idx];
    }
    __syncthreads();
#pragma unroll
    for (int i = 0; i < 4; i++)
        dst[(size_t)(c0 + ty + i * 8) * R + r0 + tx] = tile[tx][ty + i * 8];
}

// ---------------------------------------------------------------------------
// Per-head V transpose: V[(b*rpb + j)*1024 + h*64 + d] -> VT[(bh*64+d)*rpb + j]
// ---------------------------------------------------------------------------
__global__ void vtrans_k(const u16* __restrict__ V, u16* __restrict__ VT, int rpb) {
    __shared__ u16 tile[32][33];
    int bh = blockIdx.z; int b = bh >> 4, h = bh & 15;
    int j0 = blockIdx.x * 32, d0 = blockIdx.y * 32;
    int tx = threadIdx.x, ty = threadIdx.y;
#pragma unroll
    for (int i = 0; i < 4; i++)
        tile[ty + i * 8][tx] = V[(size_t)(b * rpb + j0 + ty + i * 8) * 1024 + h * 64 + d0 + tx];
    __syncthreads();
#pragma unroll
    for (int i = 0; i < 4; i++)
        VT[((size_t)bh * 64 + d0 + ty + i * 8) * rpb + j0 + tx] = tile[tx][ty + i * 8];
}

// ---------------------------------------------------------------------------
// LayerNorm over rows of 1024.
// ---------------------------------------------------------------------------
__global__ void __launch_bounds__(256) ln_kernel(
    const void* src, int sfidx, void* res_out, u16* __restrict__ xn_out,
    const u16* __restrict__ gw, const u16* __restrict__ bw,
    const u32* __restrict__ flags) {
    int row = blockIdx.x, tid = threadIdx.x;
    size_t base = (size_t)row * 1024;
    bool sf = flags[sfidx] != 0;
    bool of = flags[22] != 0;
    float v[4];
#pragma unroll
    for (int k = 0; k < 4; k++) {
        size_t idx = base + tid + k * 256;
        v[k] = sf ? ((const float*)src)[idx] : bf2f(((const u16*)src)[idx]);
    }
    if (res_out) {
#pragma unroll
        for (int k = 0; k < 4; k++) {
            size_t idx = base + tid + k * 256;
            if (of) ((float*)res_out)[idx] = v[k];
            else ((u16*)res_out)[idx] = f2bf(v[k]);
        }
    }
    float s = 0.f, ss = 0.f;
#pragma unroll
    for (int k = 0; k < 4; k++) { s += v[k]; ss += v[k] * v[k]; }
    for (int off = 32; off; off >>= 1) {
        s += __shfl_down(s, off);
        ss += __shfl_down(ss, off);
    }
    __shared__ float rs[4], rss[4];
    int wave = tid >> 6, lane = tid & 63;
    if (lane == 0) { rs[wave] = s; rss[wave] = ss; }
    __syncthreads();
    s = rs[0] + rs[1] + rs[2] + rs[3];
    ss = rss[0] + rss[1] + rss[2] + rss[3];
    float mean = s * (1.f / 1024.f);
    float var = ss * (1.f / 1024.f) - mean * mean;
    float rstd = rsqrtf(var + 1e-5f);
#pragma unroll
    for (int k = 0; k < 4; k++) {
        int c = tid + k * 256;
        xn_out[base + c] = f2bf((v[k] - mean) * rstd * bf2f(gw[c]) + bf2f(bw[c]));
    }
}

// ---------------------------------------------------------------------------
// 128x128-tile bf16 MFMA GEMM, BK=64, async global_load_lds width-16 staging
// into two planes [2][128][32] (round-5 best-measured config).
// MODE 0: Cout(bf16) = acc + bias?
// MODE 1: Res(dtype flags[22]) = acc + bias + Res  (in-place residual)
// MODE 3: Cout(bf16) = (acc + bias) * gelu(Gbuf)
// ---------------------------------------------------------------------------
template <int MODE>
__global__ void __launch_bounds__(256) gemm128(
    const u16* __restrict__ A, const u16* __restrict__ BT,
    u16* Cout, void* Res, const u16* __restrict__ bias, const u16* Gbuf,
    const u32* __restrict__ flags, int M, int N, int K) {
    __shared__ alignas(16) u16 As[2][128 * 32];
    __shared__ alignas(16) u16 Bs[2][128 * 32];
    int tid = threadIdx.x;
    int row0 = blockIdx.y * 128, col0 = blockIdx.x * 128;
    int wave = tid >> 6, lane = tid & 63, q = lane >> 4, ln = lane & 15;
    int wr = (wave >> 1) * 64, wc = (wave & 1) * 64;
    int l4r = lane >> 2, l4c = (lane & 3) * 8;   // staging: 4 lanes/row
    bool of = (MODE == 1) ? (flags[22] != 0) : false;

    f32x4 acc[4][4] = {};

    for (int k0 = 0; k0 < K; k0 += 64) {
#pragma unroll
        for (int half = 0; half < 2; half++) {
#pragma unroll
            for (int it = 0; it < 2; it++) {
                int rbase = wave * 32 + it * 16;
                int r = rbase + l4r;
                async16(A + (size_t)(row0 + r) * K + k0 + half * 32 + l4c,
                        &As[half][rbase * 32]);
                async16(BT + (size_t)(col0 + r) * K + k0 + half * 32 + l4c,
                        &Bs[half][rbase * 32]);
            }
        }
        __syncthreads();
#pragma unroll
        for (int kk = 0; kk < 2; kk++) {
            bf16x8 af[4], bfr[4];
#pragma unroll
            for (int mi = 0; mi < 4; mi++)
                af[mi] = *(const bf16x8*)(&As[kk][(wr + mi * 16 + ln) * 32 + q * 8]);
#pragma unroll
            for (int ni = 0; ni < 4; ni++)
                bfr[ni] = *(const bf16x8*)(&Bs[kk][(wc + ni * 16 + ln) * 32 + q * 8]);
#pragma unroll
            for (int mi = 0; mi < 4; mi++)
#pragma unroll
                for (int ni = 0; ni < 4; ni++)
                    acc[mi][ni] = __builtin_amdgcn_mfma_f32_16x16x32_bf16(
                        af[mi], bfr[ni], acc[mi][ni], 0, 0, 0);
        }
        __syncthreads();
    }

#pragma unroll
    for (int mi = 0; mi < 4; mi++) {
#pragma unroll
        for (int ni = 0; ni < 4; ni++) {
            int col = col0 + wc + ni * 16 + ln;
            float bv = bias ? bf2f(bias[col]) : 0.f;
#pragma unroll
            for (int r = 0; r < 4; r++) {
                int row = row0 + wr + mi * 16 + q * 4 + r;
                size_t idx = (size_t)row * N + col;
                float v = acc[mi][ni][r] + bv;
                if (MODE == 0) {
                    Cout[idx] = f2bf(v);
                } else if (MODE == 1) {
                    if (of) {
                        float* R = (float*)Res;
                        R[idx] = v + R[idx];
                    } else {
                        u16* R = (u16*)Res;
                        R[idx] = f2bf(v + bf2f(R[idx]));
                    }
                } else {  // MODE 3
                    float g = bf2f(Gbuf[idx]);
                    float ge = 0.5f * g * (1.f + erff(g * 0.70710678118f));
                    Cout[idx] = f2bf(v * ge);
                }
            }
        }
    }
}

// ---------------------------------------------------------------------------
// 256x128-tile bf16 MFMA GEMM, BK=32. 4 waves, wave tile 128x64 (8x4 acc).
// Halves LDS bytes per FLOP vs 64x64 wave tile (LDS-port ceiling 41% -> 64%)
// and halves barriers per FLOP. ~200 VGPR -> 2 waves/SIMD.
// MODE 0: Cout = acc + bias?   MODE 3: Cout = (acc+bias)*gelu(Gbuf)
// M%256==0, N%128==0, K%32==0.
// ---------------------------------------------------------------------------
template <int MODE>
__global__ void __launch_bounds__(256, 2) gemm256(
    const u16* __restrict__ A, const u16* __restrict__ BT,
    u16* Cout, const u16* __restrict__ bias, const u16* Gbuf,
    int M, int N, int K) {
    __shared__ alignas(16) u16 As[256 * 32];
    __shared__ alignas(16) u16 Bs[128 * 32];
    int tid = threadIdx.x;
    int row0 = blockIdx.y * 256, col0 = blockIdx.x * 128;
    int wave = tid >> 6, lane = tid & 63, q = lane >> 4, ln = lane & 15;
    int wr = (wave >> 1) * 128, wc = (wave & 1) * 64;
    int l4r = lane >> 2, l4c = (lane & 3) * 8;

    // hoisted staging pointers
    const u16* pA = A + (size_t)(row0 + wave * 64 + l4r) * K + l4c;
    const u16* pB = BT + (size_t)(col0 + wave * 32 + l4r) * K + l4c;
    u16* lA[4]; u16* lB[2];
#pragma unroll
    for (int it = 0; it < 4; it++) lA[it] = &As[(wave * 64 + it * 16) * 32];
#pragma unroll
    for (int it = 0; it < 2; it++) lB[it] = &Bs[(wave * 32 + it * 16) * 32];
    const size_t rStep = (size_t)16 * K;

    f32x4 acc[8][4] = {};

    for (int k0 = 0; k0 < K; k0 += 32) {
#pragma unroll
        for (int it = 0; it < 4; it++) async16(pA + it * rStep, lA[it]);
#pragma unroll
        for (int it = 0; it < 2; it++) async16(pB + it * rStep, lB[it]);
        pA += 32; pB += 32;
        __syncthreads();
        bf16x8 af[8], bfr[4];
#pragma unroll
        for (int mi = 0; mi < 8; mi++)
            af[mi] = *(const bf16x8*)(&As[(wr + mi * 16 + ln) * 32 + q * 8]);
#pragma unroll
        for (int ni = 0; ni < 4; ni++)
            bfr[ni] = *(const bf16x8*)(&Bs[(wc + ni * 16 + ln) * 32 + q * 8]);
#pragma unroll
        for (int mi = 0; mi < 8; mi++)
#pragma unroll
            for (int ni = 0; ni < 4; ni++)
                acc[mi][ni] = __builtin_amdgcn_mfma_f32_16x16x32_bf16(
                    af[mi], bfr[ni], acc[mi][ni], 0, 0, 0);
        __syncthreads();
    }

#pragma unroll
    for (int mi = 0; mi < 8; mi++) {
#pragma unroll
        for (int ni = 0; ni < 4; ni++) {
            int col = col0 + wc + ni * 16 + ln;
            float bv = bias ? bf2f(bias[col]) : 0.f;
#pragma unroll
            for (int r = 0; r < 4; r++) {
                int row = row0 + wr + mi * 16 + q * 4 + r;
                size_t idx = (size_t)row * N + col;
                float v = acc[mi][ni][r] + bv;
                if (MODE == 0) {
                    Cout[idx] = f2bf(v);
                } else {  // MODE 3
                    float g = bf2f(Gbuf[idx]);
                    float ge = 0.5f * g * (1.f + erff(g * 0.70710678118f));
                    Cout[idx] = f2bf(v * ge);
                }
            }
        }
    }
}

// ---------------------------------------------------------------------------
// Flash attention: O in place over Q. K [rows][1024]; VT per-head [64][vt_ld].
// Async width-16 staging into two-plane LDS tiles [2][64][32].
// No-running-max softmax (scores bounded for this problem), deferred row-sum.
// grid (32 q-tiles, 64 batch*head), block 256.
// ---------------------------------------------------------------------------
__global__ void __launch_bounds__(256) attn_kernel(
    u16* Q, const u16* __restrict__ K, const u16* __restrict__ VT,
    int nkv, int kv_rpb, int vt_ld, float scale) {
    __shared__ alignas(16) u16 ktile[2][64 * 32];
    __shared__ alignas(16) u16 vtile[2][64 * 32];
    __shared__ alignas(16) u16 pbuf[4][16 * 72];

    int tid = threadIdx.x, wave = tid >> 6, lane = tid & 63;
    int q = lane >> 4, ln = lane & 15;
    int l4r = lane >> 2, l4c = (lane & 3) * 8;
    int bh = blockIdx.y; int b = bh >> 4, h = bh & 15;
    int qt = blockIdx.x;
    int qrow0 = b * 2048 + qt * 64 + wave * 16;

    u16* Qbase = Q + (size_t)(qrow0 + ln) * 1024 + h * 64;
    bf16x8 qf0 = *(const bf16x8*)(Qbase + q * 8);
    bf16x8 qf1 = *(const bf16x8*)(Qbase + 32 + q * 8);

    f32x4 oacc[4] = {};
    float lsum[4] = {0.f, 0.f, 0.f, 0.f};

    const u16* Kb = K + (size_t)b * kv_rpb * 1024 + h * 64;
    const u16* VTb = VT + (size_t)bh * 64 * vt_ld;
    int nkt = (nkv + 63) >> 6;

    for (int t = 0; t < nkt; ++t) {
        int j0 = t * 64;
        int rbase = wave * 16;
#pragma unroll
        for (int half = 0; half < 2; half++) {
            async16(Kb + (size_t)(j0 + rbase + l4r) * 1024 + half * 32 + l4c,
                    &ktile[half][rbase * 32]);
            async16(VTb + (size_t)(rbase + l4r) * vt_ld + j0 + half * 32 + l4c,
                    &vtile[half][rbase * 32]);
        }
        __syncthreads();

        f32x4 s[4] = {};
#pragma unroll
        for (int ni = 0; ni < 4; ni++) {
            bf16x8 k0f = *(const bf16x8*)(&ktile[0][(ni * 16 + ln) * 32 + q * 8]);
            bf16x8 k1f = *(const bf16x8*)(&ktile[1][(ni * 16 + ln) * 32 + q * 8]);
            s[ni] = __builtin_amdgcn_mfma_f32_16x16x32_bf16(qf0, k0f, s[ni], 0, 0, 0);
            s[ni] = __builtin_amdgcn_mfma_f32_16x16x32_bf16(qf1, k1f, s[ni], 0, 0, 0);
        }

        u16* pb = pbuf[wave];
#pragma unroll
        for (int ni = 0; ni < 4; ni++) {
            bool valid = (j0 + ni * 16 + ln) < nkv;
#pragma unroll
            for (int r = 0; r < 4; r++) {
                float e = valid ? __expf(s[ni][r] * scale) : 0.f;
                lsum[r] += e;
                union { float f; u32 i; } u; u.f = e;
                pb[(q * 4 + r) * 72 + ni * 16 + ln] = (u16)(u.i >> 16);
            }
        }
        __syncthreads();

        bf16x8 pf0 = *(const bf16x8*)(pb + ln * 72 + q * 8);
        bf16x8 pf1 = *(const bf16x8*)(pb + ln * 72 + 32 + q * 8);
#pragma unroll
        for (int nd = 0; nd < 4; nd++) {
            bf16x8 v0 = *(const bf16x8*)(&vtile[0][(nd * 16 + ln) * 32 + q * 8]);
            bf16x8 v1 = *(const bf16x8*)(&vtile[1][(nd * 16 + ln) * 32 + q * 8]);
            oacc[nd] = __builtin_amdgcn_mfma_f32_16x16x32_bf16(pf0, v0, oacc[nd], 0, 0, 0);
            oacc[nd] = __builtin_amdgcn_mfma_f32_16x16x32_bf16(pf1, v1, oacc[nd], 0, 0, 0);
        }
        __syncthreads();
    }

#pragma unroll
    for (int r = 0; r < 4; r++) {
        float l = lsum[r];
        l += __shfl_xor(l, 1);
        l += __shfl_xor(l, 2);
        l += __shfl_xor(l, 4);
        l += __shfl_xor(l, 8);
        float inv = 1.f / l;
#pragma unroll
        for (int nd = 0; nd < 4; nd++)
            Q[(size_t)(qrow0 + q * 4 + r) * 1024 + h * 64 + nd * 16 + ln] =
                f2bf(oacc[nd][r] * inv);
    }
}

// ---------------------------------------------------------------------------
// Workspace layout (byte offsets).  Total 97 MiB.
// ---------------------------------------------------------------------------
static constexpr size_t MB = 1048576;
static constexpr size_t OFF_FLAGS = 0;
static constexpr size_t OFF_SMALL = 4096;
static constexpr size_t OFF_CTXP = 65536;
static constexpr size_t OFF_WT = 1 * MB;
static constexpr size_t OFF_XN = 17 * MB;
static constexpr size_t OFF_Q = 33 * MB;
static constexpr size_t OFF_K = 49 * MB;
static constexpr size_t OFF_V = 65 * MB;
static constexpr size_t OFF_VT = 81 * MB;

static constexpr int SM_BO1 = 0, SM_BO2 = 1024, SM_BFF1 = 2048, SM_BFF2 = 10240;
static constexpr int SM_G1 = 11264, SM_BE1 = 12288, SM_G2 = 13312, SM_BE2 = 14336;
static constexpr int SM_G3 = 15360, SM_BE3 = 16384;
static constexpr int SM_TOTAL = 17408;

extern "C" void kernel_launch(void* const* d_in, const int* in_sizes, int n_in,
                              void* d_out, int out_size, void* d_ws, size_t ws_size,
                              hipStream_t stream) {
    (void)out_size; (void)ws_size; (void)n_in;
    char* w = (char*)d_ws;
    u32* flags = (u32*)(w + OFF_FLAGS);
    u16* SM = (u16*)(w + OFF_SMALL);
    u16* ctxp = (u16*)(w + OFF_CTXP);
    u16* WT = (u16*)(w + OFF_WT);
    u16* xn = (u16*)(w + OFF_XN);
    u16* Qb = (u16*)(w + OFF_Q);
    u16* Kb = (u16*)(w + OFF_K);
    u16* Vb = (u16*)(w + OFF_V);
    u16* VTb = (u16*)(w + OFF_VT);
    u16* hb = Qb;  // [8192][4096] spans Q..97MB (stage 3)

    InPtrs ip;
    for (int i = 0; i < 22; i++) { ip.p[i] = d_in[i]; ip.n[i] = in_sizes[i]; }
    sniff_k<<<22, 256, 0, stream>>>(ip, flags);

    ConvDesc cd;
    const int srcs[10] = {6, 11, 13, 15, 16, 17, 18, 19, 20, 21};
    const int lens[10] = {1024, 1024, 8192, 1024, 1024, 1024, 1024, 1024, 1024, 1024};
    for (int i = 0; i < 10; i++) { cd.src[i] = d_in[srcs[i]]; cd.fidx[i] = srcs[i]; cd.n[i] = lens[i]; }
    convall_k<<<(SM_TOTAL + 255) / 256, 256, 0, stream>>>(cd, flags, SM, SM_TOTAL);

    hipMemsetAsync(ctxp, 0, 512ull * 768 * 2, stream);
    ctxcopy_k<<<(4 * 77 * 768 + 255) / 256, 256, 0, stream>>>(d_in[1], flags, ctxp);

    dim3 b32(32, 8);
    const size_t M1 = 1048576;

    // ---------------- stage 1: self attention ----------------
    transpose_k<<<dim3(32, 32), b32, 0, stream>>>(d_in[2], flags, 2, 1024, 1024, 1024, WT + 0 * M1);
    transpose_k<<<dim3(32, 32), b32, 0, stream>>>(d_in[3], flags, 3, 1024, 1024, 1024, WT + 1 * M1);
    transpose_k<<<dim3(32, 32), b32, 0, stream>>>(d_in[4], flags, 4, 1024, 1024, 1024, WT + 2 * M1);
    transpose_k<<<dim3(32, 32), b32, 0, stream>>>(d_in[5], flags, 5, 1024, 1024, 1024, WT + 3 * M1);

    ln_kernel<<<8192, 256, 0, stream>>>(d_in[0], 0, d_out, xn, SM + SM_G1, SM + SM_BE1, flags);
    gemm128<0><<<dim3(8, 64), 256, 0, stream>>>(xn, WT + 0 * M1, Qb, nullptr, nullptr, nullptr, flags, 8192, 1024, 1024);
    gemm128<0><<<dim3(8, 64), 256, 0, stream>>>(xn, WT + 1 * M1, Kb, nullptr, nullptr, nullptr, flags, 8192, 1024, 1024);
    gemm128<0><<<dim3(8, 64), 256, 0, stream>>>(xn, WT + 2 * M1, Vb, nullptr, nullptr, nullptr, flags, 8192, 1024, 1024);
    vtrans_k<<<dim3(64, 2, 64), b32, 0, stream>>>(Vb, VTb, 2048);
    attn_kernel<<<dim3(32, 64), 256, 0, stream>>>(Qb, Kb, VTb, 2048, 2048, 2048, 0.125f);
    gemm128<1><<<dim3(8, 64), 256, 0, stream>>>(Qb, WT + 3 * M1, nullptr, d_out, SM + SM_BO1, nullptr, flags, 8192, 1024, 1024);

    // ---------------- stage 2: cross attention ----------------
    transpose_k<<<dim3(32, 32), b32, 0, stream>>>(d_in[7], flags, 7, 1024, 1024, 1024, WT + 0 * M1);
    transpose_k<<<dim3(32, 24), b32, 0, stream>>>(d_in[8], flags, 8, 768, 1024, 1024, WT + 1 * M1);
    transpose_k<<<dim3(32, 24), b32, 0, stream>>>(d_in[9], flags, 9, 768, 1024, 1024, WT + 2 * M1);
    transpose_k<<<dim3(32, 32), b32, 0, stream>>>(d_in[10], flags, 10, 1024, 1024, 1024, WT + 3 * M1);

    ln_kernel<<<8192, 256, 0, stream>>>(d_out, 22, nullptr, xn, SM + SM_G2, SM + SM_BE2, flags);
    gemm128<0><<<dim3(8, 64), 256, 0, stream>>>(xn, WT + 0 * M1, Qb, nullptr, nullptr, nullptr, flags, 8192, 1024, 1024);
    gemm128<0><<<dim3(8, 4), 256, 0, stream>>>(ctxp, WT + 1 * M1, Kb, nullptr, nullptr, nullptr, flags, 512, 1024, 768);
    gemm128<0><<<dim3(8, 4), 256, 0, stream>>>(ctxp, WT + 2 * M1, Vb, nullptr, nullptr, nullptr, flags, 512, 1024, 768);
    vtrans_k<<<dim3(4, 2, 64), b32, 0, stream>>>(Vb, VTb, 128);
    attn_kernel<<<dim3(32, 64), 256, 0, stream>>>(Qb, Kb, VTb, 77, 128, 128, 0.125f);
    gemm128<1><<<dim3(8, 64), 256, 0, stream>>>(Qb, WT + 3 * M1, nullptr, d_out, SM + SM_BO2, nullptr, flags, 8192, 1024, 1024);

    // ---------------- stage 3: GEGLU FF ----------------
    ln_kernel<<<8192, 256, 0, stream>>>(d_out, 22, nullptr, xn, SM + SM_G3, SM + SM_BE3, flags);
    transpose_k<<<dim3(256, 32), b32, 0, stream>>>(d_in[12], flags, 12, 1024, 8192, 8192, WT);
    // g half (256x128 tiles): grid (N/128, M/256) = (32, 32)
    gemm256<0><<<dim3(32, 32), 256, 0, stream>>>(xn, WT + 4096ull * 1024, hb, SM + SM_BFF1 + 4096, nullptr, 8192, 4096, 1024);
    // a half fused with gelu(g), in place over h
    gemm256<3><<<dim3(32, 32), 256, 0, stream>>>(xn, WT, hb, SM + SM_BFF1, hb, 8192, 4096, 1024);
    transpose_k<<<dim3(32, 128), b32, 0, stream>>>(d_in[14], flags, 14, 4096, 1024, 1024, WT);
    gemm128<1><<<dim3(8, 64), 256, 0, stream>>>(hb, WT, nullptr, d_out, SM + SM_BFF2, nullptr, flags, 8192, 1024, 4096);
}

// Round 8
// 943.774 us; speedup vs baseline: 1.1080x; 1.0752x over previous
//
#include <hip/hip_runtime.h>

typedef unsigned short u16;
typedef unsigned int u32;
typedef short bf16x8 __attribute__((ext_vector_type(8)));
typedef float f32x4 __attribute__((ext_vector_type(4)));

__device__ __forceinline__ float bf2f(u16 h) {
    union { u32 i; float f; } v; v.i = ((u32)h) << 16; return v.f;
}
__device__ __forceinline__ u16 f2bf(float f) {
    union { float f; u32 i; } v; v.f = f;
    u32 i = v.i;
    return (u16)((i + 0x7fffu + ((i >> 16) & 1u)) >> 16);
}

// Async global->LDS 16B per lane. LDS dest = wave-uniform base + lane*16.
typedef __attribute__((address_space(1))) const unsigned int ga_u32;
typedef __attribute__((address_space(3))) unsigned int ls_u32;
__device__ __forceinline__ void async16(const void* g, void* l) {
    __builtin_amdgcn_global_load_lds((ga_u32*)g, (ls_u32*)l, 16, 0, 0);
}

struct InPtrs { const void* p[22]; int n[22]; };

// ---------------------------------------------------------------------------
// Dtype sniffer (one block per tensor): flags[t]=1 if tensor t looks like
// packed f32, 0 if bf16. flags[22] = output dtype := flags[0].
// ---------------------------------------------------------------------------
__global__ void sniff_k(InPtrs ip, u32* flags) {
    int t = blockIdx.x;
    __shared__ int s_susp, s_zero;
    if (threadIdx.x == 0) { s_susp = 0; s_zero = 0; }
    __syncthreads();
    int n = ip.n[t];
    int S = n < 4096 ? n : 4096;
    const u16* p = (const u16*)ip.p[t];
    int susp = 0, zero = 0;
    for (int i = threadIdx.x; i < S; i += 256) {
        u16 w = p[i];
        if (w == 0) zero++;
        else { int e = (w >> 7) & 0xFF; if (e < 90 || e > 150) susp++; }
    }
    atomicAdd(&s_susp, susp);
    atomicAdd(&s_zero, zero);
    __syncthreads();
    if (threadIdx.x == 0) {
        float fs = (float)s_susp / (float)S;
        float fz = (float)s_zero / (float)S;
        u32 f = (fs > 0.10f || (fz > 0.30f && fz < 0.70f)) ? 1u : 0u;
        flags[t] = f;
        if (t == 0) flags[22] = f;
    }
}

// ---------------------------------------------------------------------------
// Fused small-tensor convert: 10 contiguous segments -> SM (bf16)
// ---------------------------------------------------------------------------
struct ConvDesc { const void* src[10]; int fidx[10]; int n[10]; };

__global__ void convall_k(ConvDesc cd, const u32* __restrict__ flags,
                          u16* __restrict__ dst, int total) {
    int i = blockIdx.x * 256 + threadIdx.x;
    if (i >= total) return;
    int s = 0, start = 0;
    while (i >= start + cd.n[s]) { start += cd.n[s]; s++; }
    int off = i - start;
    const void* sp = cd.src[s];
    dst[i] = flags[cd.fidx[s]] ? f2bf(((const float*)sp)[off]) : ((const u16*)sp)[off];
}

// ---------------------------------------------------------------------------
// Context copy into zero-padded [4][128][768] bf16 buffer
// ---------------------------------------------------------------------------
__global__ void ctxcopy_k(const void* ctx, const u32* __restrict__ flags,
                          u16* __restrict__ ctxp) {
    int idx = blockIdx.x * 256 + threadIdx.x;
    if (idx < 4 * 77 * 768) {
        int c = idx % 768;
        int t = (idx / 768) % 77;
        int b = idx / (768 * 77);
        u16 v = flags[1] ? f2bf(((const float*)ctx)[idx]) : ((const u16*)ctx)[idx];
        ctxp[((size_t)b * 128 + t) * 768 + c] = v;
    }
}

// ---------------------------------------------------------------------------
// Weight transpose+convert: src [R][ld] (flagged dtype) -> dst [C][R] bf16
// ---------------------------------------------------------------------------
__global__ void transpose_k(const void* src, const u32* __restrict__ flags, int fidx,
                            int R, int C, int ld, u16* __restrict__ dst) {
    __shared__ u16 tile[32][33];
    int c0 = blockIdx.x * 32, r0 = blockIdx.y * 32;
    int tx = threadIdx.x, ty = threadIdx.y;
    bool f = flags[fidx] != 0;
#pragma unroll
    for (int i = 0; i < 4; i++) {
        size_t idx = (size_t)(r0 + ty + i * 8) * ld + c0 + tx;
        tile[ty + i * 8][tx] = f ? f2bf(((const float*)src)[idx]) : ((const u16*)src)[idx];
    }
    __syncthreads();
#pragma unroll
    for (int i = 0; i < 4; i++)
        dst[(size_t)(c0 + ty + i * 8) * R + r0 + tx] = tile[tx][ty + i * 8];
}

// ---------------------------------------------------------------------------
// Per-head V transpose: V[(b*rpb + j)*1024 + h*64 + d] -> VT[(bh*64+d)*rpb + j]
// ---------------------------------------------------------------------------
__global__ void vtrans_k(const u16* __restrict__ V, u16* __restrict__ VT, int rpb) {
    __shared__ u16 tile[32][33];
    int bh = blockIdx.z; int b = bh >> 4, h = bh & 15;
    int j0 = blockIdx.x * 32, d0 = blockIdx.y * 32;
    int tx = threadIdx.x, ty = threadIdx.y;
#pragma unroll
    for (int i = 0; i < 4; i++)
        tile[ty + i * 8][tx] = V[(size_t)(b * rpb + j0 + ty + i * 8) * 1024 + h * 64 + d0 + tx];
    __syncthreads();
#pragma unroll
    for (int i = 0; i < 4; i++)
        VT[((size_t)bh * 64 + d0 + ty + i * 8) * rpb + j0 + tx] = tile[tx][ty + i * 8];
}

// ---------------------------------------------------------------------------
// LayerNorm over rows of 1024.
// ---------------------------------------------------------------------------
__global__ void __launch_bounds__(256) ln_kernel(
    const void* src, int sfidx, void* res_out, u16* __restrict__ xn_out,
    const u16* __restrict__ gw, const u16* __restrict__ bw,
    const u32* __restrict__ flags) {
    int row = blockIdx.x, tid = threadIdx.x;
    size_t base = (size_t)row * 1024;
    bool sf = flags[sfidx] != 0;
    bool of = flags[22] != 0;
    float v[4];
#pragma unroll
    for (int k = 0; k < 4; k++) {
        size_t idx = base + tid + k * 256;
        v[k] = sf ? ((const float*)src)[idx] : bf2f(((const u16*)src)[idx]);
    }
    if (res_out) {
#pragma unroll
        for (int k = 0; k < 4; k++) {
            size_t idx = base + tid + k * 256;
            if (of) ((float*)res_out)[idx] = v[k];
            else ((u16*)res_out)[idx] = f2bf(v[k]);
        }
    }
    float s = 0.f, ss = 0.f;
#pragma unroll
    for (int k = 0; k < 4; k++) { s += v[k]; ss += v[k] * v[k]; }
    for (int off = 32; off; off >>= 1) {
        s += __shfl_down(s, off);
        ss += __shfl_down(ss, off);
    }
    __shared__ float rs[4], rss[4];
    int wave = tid >> 6, lane = tid & 63;
    if (lane == 0) { rs[wave] = s; rss[wave] = ss; }
    __syncthreads();
    s = rs[0] + rs[1] + rs[2] + rs[3];
    ss = rss[0] + rss[1] + rss[2] + rss[3];
    float mean = s * (1.f / 1024.f);
    float var = ss * (1.f / 1024.f) - mean * mean;
    float rstd = rsqrtf(var + 1e-5f);
#pragma unroll
    for (int k = 0; k < 4; k++) {
        int c = tid + k * 256;
        xn_out[base + c] = f2bf((v[k] - mean) * rstd * bf2f(gw[c]) + bf2f(bw[c]));
    }
}

// ---------------------------------------------------------------------------
// 128x128-tile bf16 MFMA GEMM, BK=32, SINGLE-BARRIER DOUBLE-BUFFERED K-loop:
// prefetch tile t+1 (async DMA into other LDS plane) issued right after the
// barrier publishing tile t -> the vmcnt(0) drain at the next barrier waits on
// a DMA issued a full iteration earlier (latency hidden), 1 barrier/iter.
// MODE 0: Cout(bf16) = acc + bias?
// MODE 1: Res(dtype flags[22]) = acc + bias + Res  (in-place residual)
// MODE 3: Cout(bf16) = (acc + bias) * gelu(Gbuf)
// MODE 4: segmented out: Cout + (col>>10)*8388608 + row*1024 + (col&1023)
// M%128==0, N%128==0, K%32==0.
// ---------------------------------------------------------------------------
template <int MODE>
__global__ void __launch_bounds__(256) gemm128(
    const u16* __restrict__ A, const u16* __restrict__ BT,
    u16* Cout, void* Res, const u16* __restrict__ bias, const u16* Gbuf,
    const u32* __restrict__ flags, int M, int N, int K) {
    __shared__ alignas(16) u16 As[2][128 * 32];
    __shared__ alignas(16) u16 Bs[2][128 * 32];
    int tid = threadIdx.x;
    int row0 = blockIdx.y * 128, col0 = blockIdx.x * 128;
    int wave = tid >> 6, lane = tid & 63, q = lane >> 4, ln = lane & 15;
    int wr = (wave >> 1) * 64, wc = (wave & 1) * 64;
    int l4r = lane >> 2, l4c = (lane & 3) * 8;   // staging: 4 lanes/row
    bool of = (MODE == 1) ? (flags[22] != 0) : false;

    // per-wave staging pointers (wave covers rows wave*32 .. wave*32+31)
    const u16* pA = A + (size_t)(row0 + wave * 32 + l4r) * K + l4c;
    const u16* pB = BT + (size_t)(col0 + wave * 32 + l4r) * K + l4c;
    const size_t rStep = (size_t)16 * K;
    u16* lA0[2]; u16* lA1[2]; u16* lB0[2]; u16* lB1[2];
#pragma unroll
    for (int bb = 0; bb < 2; bb++) {
        lA0[bb] = &As[bb][(wave * 32) * 32];
        lA1[bb] = &As[bb][(wave * 32 + 16) * 32];
        lB0[bb] = &Bs[bb][(wave * 32) * 32];
        lB1[bb] = &Bs[bb][(wave * 32 + 16) * 32];
    }

    f32x4 acc[4][4] = {};
    int NT = K >> 5;

    // prologue: tile 0 -> plane 0
    async16(pA, lA0[0]);
    async16(pA + rStep, lA1[0]);
    async16(pB, lB0[0]);
    async16(pB + rStep, lB1[0]);

    for (int t = 0; t < NT; ++t) {
        __syncthreads();  // publishes tile t (vmcnt(0) drains DMA issued last iter)
        if (t + 1 < NT) {
            int nb = (t + 1) & 1;
            const u16* nA = pA + (size_t)(t + 1) * 32;
            const u16* nB = pB + (size_t)(t + 1) * 32;
            async16(nA, lA0[nb]);
            async16(nA + rStep, lA1[nb]);
            async16(nB, lB0[nb]);
            async16(nB + rStep, lB1[nb]);
        }
        int cb = t & 1;
        bf16x8 af[4], bfr[4];
#pragma unroll
        for (int mi = 0; mi < 4; mi++)
            af[mi] = *(const bf16x8*)(&As[cb][(wr + mi * 16 + ln) * 32 + q * 8]);
#pragma unroll
        for (int ni = 0; ni < 4; ni++)
            bfr[ni] = *(const bf16x8*)(&Bs[cb][(wc + ni * 16 + ln) * 32 + q * 8]);
#pragma unroll
        for (int mi = 0; mi < 4; mi++)
#pragma unroll
            for (int ni = 0; ni < 4; ni++)
                acc[mi][ni] = __builtin_amdgcn_mfma_f32_16x16x32_bf16(
                    af[mi], bfr[ni], acc[mi][ni], 0, 0, 0);
        // no second barrier: plane (t+1)&1 was last read in iter t-1, whose
        // reads completed before the barrier at the top of this iteration.
    }

#pragma unroll
    for (int mi = 0; mi < 4; mi++) {
#pragma unroll
        for (int ni = 0; ni < 4; ni++) {
            int col = col0 + wc + ni * 16 + ln;
            float bv = (MODE != 4 && bias) ? bf2f(bias[col]) : 0.f;
#pragma unroll
            for (int r = 0; r < 4; r++) {
                int row = row0 + wr + mi * 16 + q * 4 + r;
                float v = acc[mi][ni][r] + bv;
                if (MODE == 4) {
                    int seg = col >> 10, c2 = col & 1023;
                    Cout[(size_t)seg * 8388608 + (size_t)row * 1024 + c2] = f2bf(v);
                } else {
                    size_t idx = (size_t)row * N + col;
                    if (MODE == 0) {
                        Cout[idx] = f2bf(v);
                    } else if (MODE == 1) {
                        if (of) {
                            float* R = (float*)Res;
                            R[idx] = v + R[idx];
                        } else {
                            u16* R = (u16*)Res;
                            R[idx] = f2bf(v + bf2f(R[idx]));
                        }
                    } else {  // MODE 3
                        float g = bf2f(Gbuf[idx]);
                        float ge = 0.5f * g * (1.f + erff(g * 0.70710678118f));
                        Cout[idx] = f2bf(v * ge);
                    }
                }
            }
        }
    }
}

// ---------------------------------------------------------------------------
// Flash attention: O in place over Q. K [rows][1024]; VT per-head [64][vt_ld].
// Async width-16 staging into two-plane LDS tiles [2][64][32].
// grid (32 q-tiles, 64 batch*head), block 256.
// ---------------------------------------------------------------------------
__global__ void __launch_bounds__(256) attn_kernel(
    u16* Q, const u16* __restrict__ K, const u16* __restrict__ VT,
    int nkv, int kv_rpb, int vt_ld, float scale) {
    __shared__ alignas(16) u16 ktile[2][64 * 32];
    __shared__ alignas(16) u16 vtile[2][64 * 32];
    __shared__ alignas(16) u16 pbuf[4][16 * 72];

    int tid = threadIdx.x, wave = tid >> 6, lane = tid & 63;
    int q = lane >> 4, ln = lane & 15;
    int l4r = lane >> 2, l4c = (lane & 3) * 8;
    int bh = blockIdx.y; int b = bh >> 4, h = bh & 15;
    int qt = blockIdx.x;
    int qrow0 = b * 2048 + qt * 64 + wave * 16;

    u16* Qbase = Q + (size_t)(qrow0 + ln) * 1024 + h * 64;
    bf16x8 qf0 = *(const bf16x8*)(Qbase + q * 8);
    bf16x8 qf1 = *(const bf16x8*)(Qbase + 32 + q * 8);

    f32x4 oacc[4] = {};
    float lsum[4] = {0.f, 0.f, 0.f, 0.f};

    const u16* Kb = K + (size_t)b * kv_rpb * 1024 + h * 64;
    const u16* VTb = VT + (size_t)bh * 64 * vt_ld;
    int nkt = (nkv + 63) >> 6;

    for (int t = 0; t < nkt; ++t) {
        int j0 = t * 64;
        int rbase = wave * 16;
#pragma unroll
        for (int half = 0; half < 2; half++) {
            async16(Kb + (size_t)(j0 + rbase + l4r) * 1024 + half * 32 + l4c,
                    &ktile[half][rbase * 32]);
            async16(VTb + (size_t)(rbase + l4r) * vt_ld + j0 + half * 32 + l4c,
                    &vtile[half][rbase * 32]);
        }
        __syncthreads();

        f32x4 s[4] = {};
#pragma unroll
        for (int ni = 0; ni < 4; ni++) {
            bf16x8 k0f = *(const bf16x8*)(&ktile[0][(ni * 16 + ln) * 32 + q * 8]);
            bf16x8 k1f = *(const bf16x8*)(&ktile[1][(ni * 16 + ln) * 32 + q * 8]);
            s[ni] = __builtin_amdgcn_mfma_f32_16x16x32_bf16(qf0, k0f, s[ni], 0, 0, 0);
            s[ni] = __builtin_amdgcn_mfma_f32_16x16x32_bf16(qf1, k1f, s[ni], 0, 0, 0);
        }

        u16* pb = pbuf[wave];
#pragma unroll
        for (int ni = 0; ni < 4; ni++) {
            bool valid = (j0 + ni * 16 + ln) < nkv;
#pragma unroll
            for (int r = 0; r < 4; r++) {
                float e = valid ? __expf(s[ni][r] * scale) : 0.f;
                lsum[r] += e;
                union { float f; u32 i; } u; u.f = e;
                pb[(q * 4 + r) * 72 + ni * 16 + ln] = (u16)(u.i >> 16);
            }
        }
        __syncthreads();

        bf16x8 pf0 = *(const bf16x8*)(pb + ln * 72 + q * 8);
        bf16x8 pf1 = *(const bf16x8*)(pb + ln * 72 + 32 + q * 8);
#pragma unroll
        for (int nd = 0; nd < 4; nd++) {
            bf16x8 v0 = *(const bf16x8*)(&vtile[0][(nd * 16 + ln) * 32 + q * 8]);
            bf16x8 v1 = *(const bf16x8*)(&vtile[1][(nd * 16 + ln) * 32 + q * 8]);
            oacc[nd] = __builtin_amdgcn_mfma_f32_16x16x32_bf16(pf0, v0, oacc[nd], 0, 0, 0);
            oacc[nd] = __builtin_amdgcn_mfma_f32_16x16x32_bf16(pf1, v1, oacc[nd], 0, 0, 0);
        }
        __syncthreads();
    }

#pragma unroll
    for (int r = 0; r < 4; r++) {
        float l = lsum[r];
        l += __shfl_xor(l, 1);
        l += __shfl_xor(l, 2);
        l += __shfl_xor(l, 4);
        l += __shfl_xor(l, 8);
        float inv = 1.f / l;
#pragma unroll
        for (int nd = 0; nd < 4; nd++)
            Q[(size_t)(qrow0 + q * 4 + r) * 1024 + h * 64 + nd * 16 + ln] =
                f2bf(oacc[nd][r] * inv);
    }
}

// ---------------------------------------------------------------------------
// Workspace layout (byte offsets).  Total 97 MiB.
// Qb/Kb/Vb are 16 MiB apart (8388608 u16) -> MODE-4 segmented GEMM outputs.
// ---------------------------------------------------------------------------
static constexpr size_t MB = 1048576;
static constexpr size_t OFF_FLAGS = 0;
static constexpr size_t OFF_SMALL = 4096;
static constexpr size_t OFF_CTXP = 65536;
static constexpr size_t OFF_WT = 1 * MB;
static constexpr size_t OFF_XN = 17 * MB;
static constexpr size_t OFF_Q = 33 * MB;
static constexpr size_t OFF_K = 49 * MB;
static constexpr size_t OFF_V = 65 * MB;
static constexpr size_t OFF_VT = 81 * MB;

static constexpr int SM_BO1 = 0, SM_BO2 = 1024, SM_BFF1 = 2048, SM_BFF2 = 10240;
static constexpr int SM_G1 = 11264, SM_BE1 = 12288, SM_G2 = 13312, SM_BE2 = 14336;
static constexpr int SM_G3 = 15360, SM_BE3 = 16384;
static constexpr int SM_TOTAL = 17408;

extern "C" void kernel_launch(void* const* d_in, const int* in_sizes, int n_in,
                              void* d_out, int out_size, void* d_ws, size_t ws_size,
                              hipStream_t stream) {
    (void)out_size; (void)ws_size; (void)n_in;
    char* w = (char*)d_ws;
    u32* flags = (u32*)(w + OFF_FLAGS);
    u16* SM = (u16*)(w + OFF_SMALL);
    u16* ctxp = (u16*)(w + OFF_CTXP);
    u16* WT = (u16*)(w + OFF_WT);
    u16* xn = (u16*)(w + OFF_XN);
    u16* Qb = (u16*)(w + OFF_Q);
    u16* Kb = (u16*)(w + OFF_K);
    u16* Vb = (u16*)(w + OFF_V);
    u16* VTb = (u16*)(w + OFF_VT);
    u16* hb = Qb;  // [8192][4096] spans Q..97MB (stage 3)

    InPtrs ip;
    for (int i = 0; i < 22; i++) { ip.p[i] = d_in[i]; ip.n[i] = in_sizes[i]; }
    sniff_k<<<22, 256, 0, stream>>>(ip, flags);

    ConvDesc cd;
    const int srcs[10] = {6, 11, 13, 15, 16, 17, 18, 19, 20, 21};
    const int lens[10] = {1024, 1024, 8192, 1024, 1024, 1024, 1024, 1024, 1024, 1024};
    for (int i = 0; i < 10; i++) { cd.src[i] = d_in[srcs[i]]; cd.fidx[i] = srcs[i]; cd.n[i] = lens[i]; }
    convall_k<<<(SM_TOTAL + 255) / 256, 256, 0, stream>>>(cd, flags, SM, SM_TOTAL);

    hipMemsetAsync(ctxp, 0, 512ull * 768 * 2, stream);
    ctxcopy_k<<<(4 * 77 * 768 + 255) / 256, 256, 0, stream>>>(d_in[1], flags, ctxp);

    dim3 b32(32, 8);
    const size_t M1 = 1048576;

    // ---------------- stage 1: self attention ----------------
    // Wq1^T|Wk1^T|Wv1^T contiguous [3072][1024] for the merged QKV GEMM
    transpose_k<<<dim3(32, 32), b32, 0, stream>>>(d_in[2], flags, 2, 1024, 1024, 1024, WT + 0 * M1);
    transpose_k<<<dim3(32, 32), b32, 0, stream>>>(d_in[3], flags, 3, 1024, 1024, 1024, WT + 1 * M1);
    transpose_k<<<dim3(32, 32), b32, 0, stream>>>(d_in[4], flags, 4, 1024, 1024, 1024, WT + 2 * M1);
    transpose_k<<<dim3(32, 32), b32, 0, stream>>>(d_in[5], flags, 5, 1024, 1024, 1024, WT + 3 * M1);

    ln_kernel<<<8192, 256, 0, stream>>>(d_in[0], 0, d_out, xn, SM + SM_G1, SM + SM_BE1, flags);
    // merged QKV projection: N=3072, segmented out -> Qb/Kb/Vb
    gemm128<4><<<dim3(24, 64), 256, 0, stream>>>(xn, WT, Qb, nullptr, nullptr, nullptr, flags, 8192, 3072, 1024);
    vtrans_k<<<dim3(64, 2, 64), b32, 0, stream>>>(Vb, VTb, 2048);
    attn_kernel<<<dim3(32, 64), 256, 0, stream>>>(Qb, Kb, VTb, 2048, 2048, 2048, 0.125f);
    gemm128<1><<<dim3(8, 64), 256, 0, stream>>>(Qb, WT + 3 * M1, nullptr, d_out, SM + SM_BO1, nullptr, flags, 8192, 1024, 1024);

    // ---------------- stage 2: cross attention ----------------
    transpose_k<<<dim3(32, 32), b32, 0, stream>>>(d_in[7], flags, 7, 1024, 1024, 1024, WT + 0 * M1);
    // Wk2^T|Wv2^T contiguous [2048][768] at WT+M1
    transpose_k<<<dim3(32, 24), b32, 0, stream>>>(d_in[8], flags, 8, 768, 1024, 1024, WT + 1 * M1);
    transpose_k<<<dim3(32, 24), b32, 0, stream>>>(d_in[9], flags, 9, 768, 1024, 1024, WT + 1 * M1 + 768 * 1024);
    transpose_k<<<dim3(32, 32), b32, 0, stream>>>(d_in[10], flags, 10, 1024, 1024, 1024, WT + 3 * M1);

    ln_kernel<<<8192, 256, 0, stream>>>(d_out, 22, nullptr, xn, SM + SM_G2, SM + SM_BE2, flags);
    gemm128<0><<<dim3(8, 64), 256, 0, stream>>>(xn, WT + 0 * M1, Qb, nullptr, nullptr, nullptr, flags, 8192, 1024, 1024);
    // merged K2/V2: N=2048, segmented out -> Kb/Vb
    gemm128<4><<<dim3(16, 4), 256, 0, stream>>>(ctxp, WT + 1 * M1, Kb, nullptr, nullptr, nullptr, flags, 512, 2048, 768);
    vtrans_k<<<dim3(4, 2, 64), b32, 0, stream>>>(Vb, VTb, 128);
    attn_kernel<<<dim3(32, 64), 256, 0, stream>>>(Qb, Kb, VTb, 77, 128, 128, 0.125f);
    gemm128<1><<<dim3(8, 64), 256, 0, stream>>>(Qb, WT + 3 * M1, nullptr, d_out, SM + SM_BO2, nullptr, flags, 8192, 1024, 1024);

    // ---------------- stage 3: GEGLU FF ----------------
    ln_kernel<<<8192, 256, 0, stream>>>(d_out, 22, nullptr, xn, SM + SM_G3, SM + SM_BE3, flags);
    transpose_k<<<dim3(256, 32), b32, 0, stream>>>(d_in[12], flags, 12, 1024, 8192, 8192, WT);
    gemm128<0><<<dim3(32, 64), 256, 0, stream>>>(xn, WT + 4096ull * 1024, hb, nullptr, SM + SM_BFF1 + 4096, nullptr, flags, 8192, 4096, 1024);
    gemm128<3><<<dim3(32, 64), 256, 0, stream>>>(xn, WT, hb, nullptr, SM + SM_BFF1, hb, flags, 8192, 4096, 1024);
    transpose_k<<<dim3(32, 128), b32, 0, stream>>>(d_in[14], flags, 14, 4096, 1024, 1024, WT);
    gemm128<1><<<dim3(8, 64), 256, 0, stream>>>(hb, WT, nullptr, d_out, SM + SM_BFF2, nullptr, flags, 8192, 1024, 4096);
}